// Round 2
// baseline (239.348 us; speedup 1.0000x reference)
//
#include <hip/hip_runtime.h>
#include <stdint.h>

// SimCLR loss, B=4096, D=512, TAU=0.1.  out[0]=loss, out[1]=acc(%).
//
// Round-2 structure: exploit Gram symmetry. S_aa/S_bb are symmetric and
// S_ba = S_ab^T, so every 64x64 tile-product is computed ONCE and its softmax
// statistics are harvested in BOTH the row direction (MFMA C-layout rows) and
// the column direction (C-layout cols, reduced across q-lanes). This halves
// MFMA work and — the measured bottleneck — LDS ds_read traffic vs round 1.
//
// Grid: one block per panel pair (bi<=bj), 2080 blocks. Block holds a_i,b_i
// row panels in registers (as MFMA A-fragments), stages a_j then b_j column
// tiles in LDS, computes 2 products per staged tile (shared B-fragment), and
// writes 4 partial (m,l) vectors into a [64 slot][4096 row] buffer with a
// collision-free slot scheme:
//   target panel T, slot S:  S>=T written by block (T,S) row-direction,
//                            S< T written by block (S,T) col-direction.

#define BN 4096
#define DK 512
#define NB 64
#define NEG_BIG -1e30f

typedef __attribute__((ext_vector_type(8))) __bf16 bf16x8;
typedef __attribute__((ext_vector_type(4))) float floatx4;

__device__ __forceinline__ unsigned short f2bf(float f) {
  unsigned int u = __float_as_uint(f);
  u += 0x7fffu + ((u >> 16) & 1u);  // round-to-nearest-even
  return (unsigned short)(u >> 16);
}

__device__ __forceinline__ void mlmerge(float& m, float& l, float m2, float l2) {
  float mn = fmaxf(m, m2);
  l = l * __expf(m - mn) + l2 * __expf(m2 - mn);
  m = mn;
}

// ---------------- prep: normalize rows, bf16 pack, diag label logits -------
__global__ void __launch_bounds__(128) prep_kernel(
    const float* __restrict__ A, const float* __restrict__ Bv,
    unsigned short* __restrict__ An, unsigned short* __restrict__ Bn,
    float* __restrict__ diag, float* __restrict__ out) {
  if (blockIdx.x == 0 && threadIdx.x < 2) out[threadIdx.x] = 0.0f;
  const int row = blockIdx.x;
  const int tid = threadIdx.x;  // 128 threads x 4 floats = 512
  float4 va = ((const float4*)(A + (size_t)row * DK))[tid];
  float4 vb = ((const float4*)(Bv + (size_t)row * DK))[tid];
  float ssa = va.x * va.x + va.y * va.y + va.z * va.z + va.w * va.w;
  float ssb = vb.x * vb.x + vb.y * vb.y + vb.z * vb.z + vb.w * vb.w;
  float sab = va.x * vb.x + va.y * vb.y + va.z * vb.z + va.w * vb.w;
#pragma unroll
  for (int off = 32; off > 0; off >>= 1) {
    ssa += __shfl_xor(ssa, off);
    ssb += __shfl_xor(ssb, off);
    sab += __shfl_xor(sab, off);
  }
  __shared__ float red[3][2];
  if ((tid & 63) == 0) {
    int w = tid >> 6;
    red[0][w] = ssa; red[1][w] = ssb; red[2][w] = sab;
  }
  __syncthreads();
  ssa = red[0][0] + red[0][1];
  ssb = red[1][0] + red[1][1];
  sab = red[2][0] + red[2][1];
  float na = fmaxf(sqrtf(ssa), 1e-12f);
  float nb = fmaxf(sqrtf(ssb), 1e-12f);
  const float S = 3.16227766016838f;  // sqrt(1/TAU): MFMA dot -> logit
  float sa = S / na, sb = S / nb;
  ushort4 pa, pb;
  pa.x = f2bf(va.x * sa); pa.y = f2bf(va.y * sa);
  pa.z = f2bf(va.z * sa); pa.w = f2bf(va.w * sa);
  pb.x = f2bf(vb.x * sb); pb.y = f2bf(vb.y * sb);
  pb.z = f2bf(vb.z * sb); pb.w = f2bf(vb.w * sb);
  ((ushort4*)(An + (size_t)row * DK))[tid] = pa;
  ((ushort4*)(Bn + (size_t)row * DK))[tid] = pb;
  if (tid == 0) diag[row] = (sab / (na * nb)) * 10.0f;  // /TAU
}

// ---------------- tiles: symmetric pair blocks ----------------------------
__global__ void __launch_bounds__(256, 2) tiles_kernel(
    const unsigned short* __restrict__ An, const unsigned short* __restrict__ Bn,
    float* __restrict__ pmA, float* __restrict__ plA,
    float* __restrict__ pmB, float* __restrict__ plB) {
  // 64 cols x 512 bf16 = 64KB, XOR-swizzled in 16B chunks (see round 1).
  __shared__ __align__(16) unsigned short tile[64 * DK];

  // decode (bi, bj), bi<=bj, from linear block id
  int idx = blockIdx.x;
  int bi = 0;
  while (idx >= NB - bi) { idx -= NB - bi; ++bi; }
  const int bj = bi + idx;
  const bool diag = (bi == bj);

  const int tid = threadIdx.x;
  const int lane = tid & 63, w = tid >> 6;
  const int n = lane & 15, q = lane >> 4;
  const int r0i = bi * 64, r0j = bj * 64;

  // register-resident left fragments: a_i and b_i rows (16 rows per wave)
  // A-frag layout: lane holds A[m=lane&15][k=q*8+j] per 32-K chunk.
  bf16x8 afA[16], afB[16];
  {
    const int row = r0i + w * 16 + n;
    const unsigned short* pa = An + (size_t)row * DK + q * 8;
    const unsigned short* pb = Bn + (size_t)row * DK + q * 8;
#pragma unroll
    for (int kc = 0; kc < 16; ++kc) {
      afA[kc] = *(const bf16x8*)(pa + kc * 32);
      afB[kc] = *(const bf16x8*)(pb + kc * 32);
    }
  }

  // row-direction online state for rows of panel bi (per lane: rows q*4+r,
  // cols {cs*16+n}; n-merged at the end)
  float mRa[4], lRa[4], mRb[4], lRb[4];
#pragma unroll
  for (int r = 0; r < 4; ++r) { mRa[r] = NEG_BIG; lRa[r] = 0.f; mRb[r] = NEG_BIG; lRb[r] = 0.f; }

  // column-direction results (per cs; col = cs*16+n; q-merged over 16 rows)
  float mC0[4], lC0[4], mC1[4], lC1[4];

  const int nx = n & 7;

  for (int t = 0; t < 2; ++t) {
    const unsigned short* colsrc = (t == 0) ? An : Bn;  // a_j cols, then b_j
    __syncthreads();
#pragma unroll
    for (int ii = 0; ii < 16; ++ii) {  // wave w stages cols w*16..w*16+15
      const int cl = w * 16 + ii;
      const unsigned short* src = colsrc + (size_t)(r0j + cl) * DK;
      const int sw = (lane ^ (cl & 7)) * 8;  // swizzled 16B-chunk source
      __builtin_amdgcn_global_load_lds(
          (const __attribute__((address_space(1))) void*)(src + sw),
          (__attribute__((address_space(3))) void*)(&tile[cl * DK]),
          16, 0, 0);
    }
    __syncthreads();

    floatx4 accA[4], accB[4];
#pragma unroll
    for (int cs = 0; cs < 4; ++cs) {
      floatx4 z = {0.f, 0.f, 0.f, 0.f};
      accA[cs] = z; accB[cs] = z;
    }
#pragma unroll
    for (int kc = 0; kc < 16; ++kc) {
#pragma unroll
      for (int cs = 0; cs < 4; ++cs) {
        const int col = cs * 16 + n;
        const int phys = ((kc * 4 + q) ^ nx) * 8;
        bf16x8 bfr = *(const bf16x8*)(tile + col * DK + phys);
        accA[cs] = __builtin_amdgcn_mfma_f32_16x16x32_bf16(afA[kc], bfr, accA[cs], 0, 0, 0);
        accB[cs] = __builtin_amdgcn_mfma_f32_16x16x32_bf16(afB[kc], bfr, accB[cs], 0, 0, 0);
      }
    }

    // diag tiles: mask self positions (aa/bb masked diag; ab label diag —
    // label re-added in finalize). C layout: row=q*4+reg, col=cs*16+n.
    if (diag) {
#pragma unroll
      for (int cs = 0; cs < 4; ++cs)
#pragma unroll
        for (int r = 0; r < 4; ++r)
          if (cs == w && n == q * 4 + r) { accA[cs][r] = NEG_BIG; accB[cs][r] = NEG_BIG; }
    }

    // ---- row-direction harvest (target: rows of panel bi) ----
    // t0: accA->fa_i (aa), accB->fb_i (ba). t1: accA->fa_i (ab), accB->fb_i (bb).
    // diag t1: skip accA (P3 duplicates P2's transpose).
    if (!(diag && t == 1)) {
#pragma unroll
      for (int r = 0; r < 4; ++r) {
        float a0 = accA[0][r], a1 = accA[1][r], a2 = accA[2][r], a3 = accA[3][r];
        float vmax = fmaxf(fmaxf(a0, a1), fmaxf(a2, a3));
        float mn = fmaxf(mRa[r], vmax);
        float s = __expf(a0 - mn) + __expf(a1 - mn) + __expf(a2 - mn) + __expf(a3 - mn);
        lRa[r] = lRa[r] * __expf(mRa[r] - mn) + s;
        mRa[r] = mn;
      }
    }
#pragma unroll
    for (int r = 0; r < 4; ++r) {
      float b0 = accB[0][r], b1 = accB[1][r], b2 = accB[2][r], b3 = accB[3][r];
      float vmax = fmaxf(fmaxf(b0, b1), fmaxf(b2, b3));
      float mn = fmaxf(mRb[r], vmax);
      float s = __expf(b0 - mn) + __expf(b1 - mn) + __expf(b2 - mn) + __expf(b3 - mn);
      lRb[r] = lRb[r] * __expf(mRb[r] - mn) + s;
      mRb[r] = mn;
    }

    // ---- column-direction harvest (target: rows of panel bj) ----
    // t0 -> fa_j: accA (aa cols, skip if diag) + accB (ba cols -> full_a).
    // t1 -> fb_j: accA (ab cols -> full_b) + accB (bb cols); skip all if diag.
    if (t == 0) {
#pragma unroll
      for (int cs = 0; cs < 4; ++cs) {
        float m = NEG_BIG;
        if (!diag) {
#pragma unroll
          for (int r = 0; r < 4; ++r) m = fmaxf(m, accA[cs][r]);
        }
#pragma unroll
        for (int r = 0; r < 4; ++r) m = fmaxf(m, accB[cs][r]);
        float l = 0.f;
        if (!diag) {
#pragma unroll
          for (int r = 0; r < 4; ++r) l += __expf(accA[cs][r] - m);
        }
#pragma unroll
        for (int r = 0; r < 4; ++r) l += __expf(accB[cs][r] - m);
#pragma unroll
        for (int off = 16; off < 64; off <<= 1) {
          float mo = __shfl_xor(m, off), lo = __shfl_xor(l, off);
          float mn = fmaxf(m, mo);
          l = l * __expf(m - mn) + lo * __expf(mo - mn);
          m = mn;
        }
        mC0[cs] = m; lC0[cs] = l;
      }
    } else if (!diag) {
#pragma unroll
      for (int cs = 0; cs < 4; ++cs) {
        float m = NEG_BIG;
#pragma unroll
        for (int r = 0; r < 4; ++r) m = fmaxf(fmaxf(m, accA[cs][r]), accB[cs][r]);
        float l = 0.f;
#pragma unroll
        for (int r = 0; r < 4; ++r) l += __expf(accA[cs][r] - m) + __expf(accB[cs][r] - m);
#pragma unroll
        for (int off = 16; off < 64; off <<= 1) {
          float mo = __shfl_xor(m, off), lo = __shfl_xor(l, off);
          float mn = fmaxf(m, mo);
          l = l * __expf(m - mn) + lo * __expf(mo - mn);
          m = mn;
        }
        mC1[cs] = m; lC1[cs] = l;
      }
    }
  }

  // n-merge row state: lanes with same q cover disjoint col subsets
#pragma unroll
  for (int off = 1; off < 16; off <<= 1) {
#pragma unroll
    for (int r = 0; r < 4; ++r) {
      float mo = __shfl_xor(mRa[r], off), lo = __shfl_xor(lRa[r], off);
      float mn = fmaxf(mRa[r], mo);
      lRa[r] = lRa[r] * __expf(mRa[r] - mn) + lo * __expf(mo - mn);
      mRa[r] = mn;
      mo = __shfl_xor(mRb[r], off); lo = __shfl_xor(lRb[r], off);
      mn = fmaxf(mRb[r], mo);
      lRb[r] = lRb[r] * __expf(mRb[r] - mn) + lo * __expf(mo - mn);
      mRb[r] = mn;
    }
  }

  // reuse tile LDS as stat buffers
  __syncthreads();
  float* colbuf = (float*)tile;                 // [2][4 waves][64 cols][2]
  float* rowbuf = colbuf + 2 * 4 * 64 * 2;      // [2][64 rows][2]

  if (q == 0) {
#pragma unroll
    for (int cs = 0; cs < 4; ++cs) {
      const int c = cs * 16 + n;
      colbuf[((0 * 4 + w) * 64 + c) * 2 + 0] = mC0[cs];
      colbuf[((0 * 4 + w) * 64 + c) * 2 + 1] = lC0[cs];
      if (!diag) {
        colbuf[((1 * 4 + w) * 64 + c) * 2 + 0] = mC1[cs];
        colbuf[((1 * 4 + w) * 64 + c) * 2 + 1] = lC1[cs];
      }
    }
  }
  if (n == 0) {
#pragma unroll
    for (int r = 0; r < 4; ++r) {
      const int rr = w * 16 + q * 4 + r;
      rowbuf[(0 * 64 + rr) * 2 + 0] = mRa[r];
      rowbuf[(0 * 64 + rr) * 2 + 1] = lRa[r];
      rowbuf[(1 * 64 + rr) * 2 + 0] = mRb[r];
      rowbuf[(1 * 64 + rr) * 2 + 1] = lRb[r];
    }
  }
  __syncthreads();

  if (tid < 128) {
    const int prob = tid >> 6, tt = tid & 63;
    float* pm = prob ? pmB : pmA;
    float* pl = prob ? plB : plA;
    float rm = rowbuf[(prob * 64 + tt) * 2 + 0];
    float rl = rowbuf[(prob * 64 + tt) * 2 + 1];
    if (diag) {
      if (prob == 0) {  // fa_i: merge P1row (rowbuf) + P2col (colbuf)
        float cm = NEG_BIG, cl2 = 0.f;
#pragma unroll
        for (int wv = 0; wv < 4; ++wv)
          mlmerge(cm, cl2, colbuf[((0 * 4 + wv) * 64 + tt) * 2 + 0],
                           colbuf[((0 * 4 + wv) * 64 + tt) * 2 + 1]);
        mlmerge(rm, rl, cm, cl2);
      }  // fb_i diag = P2row + P4row, already merged in row state
      pm[(size_t)bi * BN + r0i + tt] = rm;
      pl[(size_t)bi * BN + r0i + tt] = rl;
    } else {
      float cm = NEG_BIG, cl2 = 0.f;
#pragma unroll
      for (int wv = 0; wv < 4; ++wv)
        mlmerge(cm, cl2, colbuf[((prob * 4 + wv) * 64 + tt) * 2 + 0],
                         colbuf[((prob * 4 + wv) * 64 + tt) * 2 + 1]);
      pm[(size_t)bj * BN + r0i + tt] = rm;   // row-dir: rows bi, slot bj
      pl[(size_t)bj * BN + r0i + tt] = rl;
      pm[(size_t)bi * BN + r0j + tt] = cm;   // col-dir: rows bj, slot bi
      pl[(size_t)bi * BN + r0j + tt] = cl2;
    }
  }
}

// ---------------- finalize: merge 64 slots, add label, reduce -------------
__global__ void __launch_bounds__(256) finalize_kernel(
    const float* __restrict__ pmA, const float* __restrict__ plA,
    const float* __restrict__ pmB, const float* __restrict__ plB,
    const float* __restrict__ diag, float* __restrict__ out) {
  const int row = blockIdx.x * 256 + threadIdx.x;
  float Ma = NEG_BIG, La = 0.f, Mb = NEG_BIG, Lb = 0.f;
#pragma unroll 4
  for (int s = 0; s < NB; ++s) {
    mlmerge(Ma, La, pmA[(size_t)s * BN + row], plA[(size_t)s * BN + row]);
    mlmerge(Mb, Lb, pmB[(size_t)s * BN + row], plB[(size_t)s * BN + row]);
  }
  const float d = diag[row];
  float corr = (d >= Ma) ? 1.f : 0.f;  // argmax(full_a)==label
  float mna = fmaxf(Ma, d);
  float lseA = mna + logf(La * __expf(Ma - mna) + __expf(d - mna));
  float mnb = fmaxf(Mb, d);
  float lseB = mnb + logf(Lb * __expf(Mb - mnb) + __expf(d - mnb));
  float lossi = (lseA - d) + (lseB - d);
#pragma unroll
  for (int off = 32; off > 0; off >>= 1) {
    lossi += __shfl_xor(lossi, off);
    corr += __shfl_xor(corr, off);
  }
  __shared__ float sred[2][4];
  if ((threadIdx.x & 63) == 0) {
    int w = threadIdx.x >> 6;
    sred[0][w] = lossi; sred[1][w] = corr;
  }
  __syncthreads();
  if (threadIdx.x == 0) {
    float ls = sred[0][0] + sred[0][1] + sred[0][2] + sred[0][3];
    float cs = sred[1][0] + sred[1][1] + sred[1][2] + sred[1][3];
    atomicAdd(&out[0], ls * (1.0f / 8192.0f));    // mean over rows, /2
    atomicAdd(&out[1], cs * (100.0f / 4096.0f));  // accuracy %
  }
}

extern "C" void kernel_launch(void* const* d_in, const int* in_sizes, int n_in,
                              void* d_out, int out_size, void* d_ws, size_t ws_size,
                              hipStream_t stream) {
  const float* A = (const float*)d_in[0];
  const float* Bv = (const float*)d_in[1];
  unsigned short* An = (unsigned short*)d_ws;                 // 4096x512 bf16
  unsigned short* Bn = An + (size_t)BN * DK;                  // 4096x512 bf16
  float* diag = (float*)(Bn + (size_t)BN * DK);               // 4096 f32
  float* pmA = diag + BN;                                     // [64][4096] f32 each
  float* plA = pmA + (size_t)NB * BN;
  float* pmB = plA + (size_t)NB * BN;
  float* plB = pmB + (size_t)NB * BN;
  float* out = (float*)d_out;

  prep_kernel<<<BN, 128, 0, stream>>>(A, Bv, An, Bn, diag, out);
  tiles_kernel<<<NB * (NB + 1) / 2, 256, 0, stream>>>(An, Bn, pmA, plA, pmB, plB);
  finalize_kernel<<<BN / 256, 256, 0, stream>>>(pmA, plA, pmB, plB, diag, out);
}

// Round 3
// 159.733 us; speedup vs baseline: 1.4984x; 1.4984x over previous
//
#include <hip/hip_runtime.h>
#include <stdint.h>

// SimCLR loss, B=4096, D=512, TAU=0.1.  out[0]=loss, out[1]=acc(%).
//
// Round 3: round-1 streaming structure (proven low-FETCH, correct), inner
// compute upgraded 16x16x32 -> 32x32x16 MFMA. 32 rows/wave of register-
// resident left fragments doubles MACs per staged-LDS byte (the round-1
// measured bottleneck: LDS pipe 5:1 over MFMA). 128-row blocks, 1 block/CU,
// LDS double-buffer (2 x 64 KB dynamic) to hide staging behind compute.

#define BN 4096
#define DK 512
#define NSPLIT 8
#define NEG_BIG -1e30f
#define TILE_ELEMS (64 * DK)  // one 64-col x 512-K bf16 tile

typedef __attribute__((ext_vector_type(8))) __bf16 bf16x8;
typedef __attribute__((ext_vector_type(16))) float floatx16;

__device__ __forceinline__ unsigned short f2bf(float f) {
  unsigned int u = __float_as_uint(f);
  u += 0x7fffu + ((u >> 16) & 1u);  // round-to-nearest-even
  return (unsigned short)(u >> 16);
}

__device__ __forceinline__ void mlmerge(float& m, float& l, float m2, float l2) {
  float mn = fmaxf(m, m2);
  l = l * __expf(m - mn) + l2 * __expf(m2 - mn);
  m = mn;
}

// ---------------- prep: one wave per row, shfl-only reduction -------------
__global__ void __launch_bounds__(256) prep_kernel(
    const float* __restrict__ A, const float* __restrict__ Bv,
    unsigned short* __restrict__ An, unsigned short* __restrict__ Bn,
    float* __restrict__ diag, float* __restrict__ out) {
  if (blockIdx.x == 0 && threadIdx.x < 2) out[threadIdx.x] = 0.0f;
  const int w = threadIdx.x >> 6, lane = threadIdx.x & 63;
  const int row = blockIdx.x * 4 + w;
  const float4* pa4 = (const float4*)(A + (size_t)row * DK);
  const float4* pb4 = (const float4*)(Bv + (size_t)row * DK);
  float4 a0 = pa4[lane], a1 = pa4[lane + 64];
  float4 b0 = pb4[lane], b1 = pb4[lane + 64];
  float ssa = a0.x * a0.x + a0.y * a0.y + a0.z * a0.z + a0.w * a0.w +
              a1.x * a1.x + a1.y * a1.y + a1.z * a1.z + a1.w * a1.w;
  float ssb = b0.x * b0.x + b0.y * b0.y + b0.z * b0.z + b0.w * b0.w +
              b1.x * b1.x + b1.y * b1.y + b1.z * b1.z + b1.w * b1.w;
  float sab = a0.x * b0.x + a0.y * b0.y + a0.z * b0.z + a0.w * b0.w +
              a1.x * b1.x + a1.y * b1.y + a1.z * b1.z + a1.w * b1.w;
#pragma unroll
  for (int off = 32; off > 0; off >>= 1) {
    ssa += __shfl_xor(ssa, off);
    ssb += __shfl_xor(ssb, off);
    sab += __shfl_xor(sab, off);
  }
  float na = fmaxf(sqrtf(ssa), 1e-12f);
  float nb = fmaxf(sqrtf(ssb), 1e-12f);
  const float S = 3.16227766016838f;  // sqrt(1/TAU): MFMA dot -> logit
  float sa = S / na, sb = S / nb;
  ushort4 p;
  p.x = f2bf(a0.x * sa); p.y = f2bf(a0.y * sa); p.z = f2bf(a0.z * sa); p.w = f2bf(a0.w * sa);
  ((ushort4*)(An + (size_t)row * DK))[lane] = p;
  p.x = f2bf(a1.x * sa); p.y = f2bf(a1.y * sa); p.z = f2bf(a1.z * sa); p.w = f2bf(a1.w * sa);
  ((ushort4*)(An + (size_t)row * DK))[lane + 64] = p;
  p.x = f2bf(b0.x * sb); p.y = f2bf(b0.y * sb); p.z = f2bf(b0.z * sb); p.w = f2bf(b0.w * sb);
  ((ushort4*)(Bn + (size_t)row * DK))[lane] = p;
  p.x = f2bf(b1.x * sb); p.y = f2bf(b1.y * sb); p.z = f2bf(b1.z * sb); p.w = f2bf(b1.w * sb);
  ((ushort4*)(Bn + (size_t)row * DK))[lane + 64] = p;
  if (lane == 0) diag[row] = (sab / (na * nb)) * 10.0f;  // /TAU
}

// ---------------- tiles: 128-row blocks, 32x32x16 MFMA, dbuf LDS ----------
// Unified column space: jt<64 -> A_n cols, jt>=64 -> B_n cols (64 cols/tile).
//   accA = a_rows . cols (full_a), accB = b_rows . cols (full_b).
// Both problems exclude (i,i) of both halves; fp32 label re-added in finalize.
// grid = (32 row-blocks, 8 col-splits) = 256 blocks = 1/CU. block = 4 waves,
// each wave owns 32 rows; left frags (full K, both views) live in registers.
__global__ void __launch_bounds__(256, 1) tiles_kernel(
    const unsigned short* __restrict__ An, const unsigned short* __restrict__ Bn,
    float* __restrict__ pmA, float* __restrict__ plA,
    float* __restrict__ pmB, float* __restrict__ plB) {
  extern __shared__ __align__(16) unsigned short smem[];  // 2 x 64KB tiles

  const int rb = blockIdx.x;     // 0..31 (128-row panel)
  const int split = blockIdx.y;  // 0..7  (16 j-tiles each)
  const int tid = threadIdx.x;
  const int lane = tid & 63, w = tid >> 6;
  const int n5 = lane & 31, h = lane >> 5, nx = n5 & 7;
  const int r0 = rb * 128;

  // ---- persistent left fragments: 32 rows/wave, full K, both views ----
  // A-frag layout (32x32x16): lane holds A[m=lane&31][k=kc*16 + h*8 + j].
  bf16x8 afA[32], afB[32];
  {
    const int myrow = r0 + w * 32 + n5;
    const unsigned short* pa = An + (size_t)myrow * DK + h * 8;
    const unsigned short* pb = Bn + (size_t)myrow * DK + h * 8;
#pragma unroll
    for (int kc = 0; kc < 32; ++kc) {
      afA[kc] = *(const bf16x8*)(pa + kc * 16);
      afB[kc] = *(const bf16x8*)(pb + kc * 16);
    }
  }

  // C/D layout (32x32): col = lane&31, row = (reg&3) + 8*(reg>>2) + 4*h.
  // Online-softmax state per lane: 16 row slots x 2 problems.
  float mA[16], lA[16], mB[16], lB[16];
#pragma unroll
  for (int r = 0; r < 16; ++r) { mA[r] = NEG_BIG; lA[r] = 0.f; mB[r] = NEG_BIG; lB[r] = 0.f; }

  // stage one 64-col tile into buf; wave w stages cols w*16..w*16+15.
  // XOR swizzle: physical 16B-chunk p of col c holds logical chunk p^(c&7).
  auto stage = [&](unsigned short* buf, int jt) {
    const unsigned short* csrc = (jt < 64) ? An : Bn;
    const int cb = (jt & 63) * 64;
#pragma unroll
    for (int ii = 0; ii < 16; ++ii) {
      const int cl = w * 16 + ii;
      const unsigned short* src =
          csrc + (size_t)(cb + cl) * DK + ((lane ^ (cl & 7)) * 8);
      __builtin_amdgcn_global_load_lds(
          (const __attribute__((address_space(1))) void*)src,
          (__attribute__((address_space(3))) void*)(buf + cl * DK),
          16, 0, 0);
    }
  };

  stage(smem, split * 16);
  __syncthreads();

  for (int t = 0; t < 16; ++t) {
    const int jt = split * 16 + t;
    unsigned short* cur = smem + (t & 1) * TILE_ELEMS;
    unsigned short* nxt = smem + ((t + 1) & 1) * TILE_ELEMS;
    if (t < 15) stage(nxt, jt + 1);  // prefetch; drained at this iter's barrier

    floatx16 accA[2], accB[2];
#pragma unroll
    for (int cs = 0; cs < 2; ++cs)
#pragma unroll
      for (int r = 0; r < 16; ++r) { accA[cs][r] = 0.f; accB[cs][r] = 0.f; }

    // B-frag (32x32x16): lane reads B[k=kc*16+h*8+j][n=cs*32+n5]
    //  = col (cs*32+n5)'s logical 16B chunk (kc*2+h), physical ^(n5&7).
    const unsigned short* b0 = cur + (size_t)n5 * DK;
#pragma unroll
    for (int kc = 0; kc < 32; ++kc) {
      const int chunk = ((kc * 2 + h) ^ nx) * 8;
      bf16x8 bf0 = *(const bf16x8*)(b0 + chunk);
      bf16x8 bf1 = *(const bf16x8*)(b0 + 32 * DK + chunk);
      accA[0] = __builtin_amdgcn_mfma_f32_32x32x16_bf16(afA[kc], bf0, accA[0], 0, 0, 0);
      accB[0] = __builtin_amdgcn_mfma_f32_32x32x16_bf16(afB[kc], bf0, accB[0], 0, 0, 0);
      accA[1] = __builtin_amdgcn_mfma_f32_32x32x16_bf16(afA[kc], bf1, accA[1], 0, 0, 0);
      accB[1] = __builtin_amdgcn_mfma_f32_32x32x16_bf16(afB[kc], bf1, accB[1], 0, 0, 0);
    }

    // diag-aligned tiles: kill (i,i) of this half for BOTH problems
    if (((jt & 63) >> 1) == rb) {
      const int colbase = (jt & 63) * 64;
#pragma unroll
      for (int cs = 0; cs < 2; ++cs) {
        const int col = colbase + cs * 32 + n5;
#pragma unroll
        for (int r = 0; r < 16; ++r) {
          const int row = r0 + w * 32 + (r & 3) + 8 * (r >> 2) + 4 * h;
          if (row == col) { accA[cs][r] = NEG_BIG; accB[cs][r] = NEG_BIG; }
        }
      }
    }

    // lane-local online softmax update (16 rows x 2 cols x 2 problems)
#pragma unroll
    for (int r = 0; r < 16; ++r) {
      {
        float a0 = accA[0][r], a1 = accA[1][r];
        float mn = fmaxf(mA[r], fmaxf(a0, a1));
        lA[r] = lA[r] * __expf(mA[r] - mn) + __expf(a0 - mn) + __expf(a1 - mn);
        mA[r] = mn;
      }
      {
        float v0 = accB[0][r], v1 = accB[1][r];
        float mn = fmaxf(mB[r], fmaxf(v0, v1));
        lB[r] = lB[r] * __expf(mB[r] - mn) + __expf(v0 - mn) + __expf(v1 - mn);
        mB[r] = mn;
      }
    }
    __syncthreads();  // everyone done with cur; nxt's DMA drained (vmcnt0)
  }

  // merge across the 32 lanes (cols) of each h-group; rows identical in-group
#pragma unroll
  for (int off = 1; off < 32; off <<= 1) {
#pragma unroll
    for (int r = 0; r < 16; ++r) {
      float mo = __shfl_xor(mA[r], off), lo = __shfl_xor(lA[r], off);
      mlmerge(mA[r], lA[r], mo, lo);
      mo = __shfl_xor(mB[r], off); lo = __shfl_xor(lB[r], off);
      mlmerge(mB[r], lB[r], mo, lo);
    }
  }
  if (n5 == 0) {
    const int base = split * BN;
#pragma unroll
    for (int r = 0; r < 16; ++r) {
      const int row = r0 + w * 32 + (r & 3) + 8 * (r >> 2) + 4 * h;
      pmA[base + row] = mA[r];
      plA[base + row] = lA[r];
      pmB[base + row] = mB[r];
      plB[base + row] = lB[r];
    }
  }
}

// ---------------- finalize: merge 8 splits, add label, reduce -------------
__global__ void __launch_bounds__(256) finalize_kernel(
    const float* __restrict__ pmA, const float* __restrict__ plA,
    const float* __restrict__ pmB, const float* __restrict__ plB,
    const float* __restrict__ diag, float* __restrict__ out) {
  const int row = blockIdx.x * 256 + threadIdx.x;
  float Ma = NEG_BIG, La = 0.f, Mb = NEG_BIG, Lb = 0.f;
#pragma unroll
  for (int s = 0; s < NSPLIT; ++s) {
    mlmerge(Ma, La, pmA[s * BN + row], plA[s * BN + row]);
    mlmerge(Mb, Lb, pmB[s * BN + row], plB[s * BN + row]);
  }
  const float d = diag[row];
  float corr = (d >= Ma) ? 1.f : 0.f;  // argmax(full_a)==label
  float mna = fmaxf(Ma, d);
  float lseA = mna + logf(La * __expf(Ma - mna) + __expf(d - mna));
  float mnb = fmaxf(Mb, d);
  float lseB = mnb + logf(Lb * __expf(Mb - mnb) + __expf(d - mnb));
  float lossi = (lseA - d) + (lseB - d);
#pragma unroll
  for (int off = 32; off > 0; off >>= 1) {
    lossi += __shfl_xor(lossi, off);
    corr += __shfl_xor(corr, off);
  }
  __shared__ float sred[2][4];
  if ((threadIdx.x & 63) == 0) {
    int w = threadIdx.x >> 6;
    sred[0][w] = lossi; sred[1][w] = corr;
  }
  __syncthreads();
  if (threadIdx.x == 0) {
    float ls = sred[0][0] + sred[0][1] + sred[0][2] + sred[0][3];
    float cs = sred[1][0] + sred[1][1] + sred[1][2] + sred[1][3];
    atomicAdd(&out[0], ls * (1.0f / 8192.0f));    // mean over rows, /2
    atomicAdd(&out[1], cs * (100.0f / 4096.0f));  // accuracy %
  }
}

extern "C" void kernel_launch(void* const* d_in, const int* in_sizes, int n_in,
                              void* d_out, int out_size, void* d_ws, size_t ws_size,
                              hipStream_t stream) {
  const float* A = (const float*)d_in[0];
  const float* Bv = (const float*)d_in[1];
  unsigned short* An = (unsigned short*)d_ws;                 // 4096x512 bf16
  unsigned short* Bn = An + (size_t)BN * DK;                  // 4096x512 bf16
  float* diag = (float*)(Bn + (size_t)BN * DK);               // 4096 f32
  float* pmA = diag + BN;                                     // [8][4096] f32 each
  float* plA = pmA + NSPLIT * BN;
  float* pmB = plA + NSPLIT * BN;
  float* plB = pmB + NSPLIT * BN;
  float* out = (float*)d_out;

  prep_kernel<<<BN / 4, 256, 0, stream>>>(A, Bv, An, Bn, diag, out);
  tiles_kernel<<<dim3(32, 8), 256, 2 * TILE_ELEMS * sizeof(unsigned short), stream>>>(
      An, Bn, pmA, plA, pmB, plB);
  finalize_kernel<<<BN / 256, 256, 0, stream>>>(pmA, plA, pmB, plB, diag, out);
}